// Round 8
// baseline (706.237 us; speedup 1.0000x reference)
//
#include <hip/hip_runtime.h>
#include <math.h>

#define HH 56
#define WS_W 56
#define HWS 3136
#define CD 384
#define BB 16
#define NROW (BB*HWS)                 // 50176
#define SLOT ((size_t)NROW*CD)        // 19267584 elements

typedef __attribute__((ext_vector_type(8))) short bf16x8;
typedef __attribute__((ext_vector_type(4))) float f32x4;

__device__ inline ushort f2bf(float v) {
  uint u = __float_as_uint(v);
  uint r = (u + 0x7fffu + ((u >> 16) & 1u)) >> 16;
  return (ushort)r;
}
__device__ inline float bf2f(ushort h) { return __uint_as_float((uint)h << 16); }

// direct global -> LDS DMA, 16B per lane; LDS dest = wave-uniform base + lane*16
__device__ inline void gl16(const void* g, void* l) {
  __builtin_amdgcn_global_load_lds(
      (const __attribute__((address_space(1))) void*)g,
      (__attribute__((address_space(3))) void*)l,
      16, 0, 0);
}

// ---------------- DCT matrix ----------
__global__ void prep_d_k(float* __restrict__ D) {
  for (int idx = threadIdx.x; idx < HH*HH; idx += blockDim.x) {
    int k = idx / HH, n = idx % HH;
    double v = cos(3.14159265358979323846 * (2.0*n + 1.0) * k / (2.0*HH)) * sqrt(2.0/HH);
    if (k == 0) v *= 0.70710678118654752440;
    D[idx] = (float)v;
  }
}

// ---------------- D fragment-ready pack: [orient][hi 4096 u16][lo 4096 u16] ---
// A-operand LDS layout: off_u16 = mg*1024 + (koct*16 + m16)*8 + j
__global__ void prep_pack_k(const float* __restrict__ Dm, ushort* __restrict__ Dpk) {
  for (int idx = threadIdx.x; idx < 2*4096; idx += 256) {
    int o = idx >> 12, e = idx & 4095;
    int mg = e >> 10, rem = e & 1023;
    int j = rem & 7, km = rem >> 3;
    int koct = km >> 4, m16 = km & 15;
    int m = mg*16 + m16, k = koct*8 + j;
    float v = 0.f;
    if (m < 56 && k < 56) v = o ? Dm[k*56 + m] : Dm[m*56 + k];
    ushort h = f2bf(v);
    Dpk[o*8192 + e] = h;
    Dpk[o*8192 + 4096 + e] = f2bf(v - bf2f(h));
  }
}

// ---------------- weight split fp32 -> bf16 hi/lo ----------------
__global__ __launch_bounds__(256) void split_w_k(
    const float* __restrict__ W, ushort* __restrict__ hi,
    ushort* __restrict__ lo, int nelem) {
  int i = blockIdx.x*256 + threadIdx.x;
  if (i >= nelem) return;
  float v = W[i];
  ushort h = f2bf(v);
  hi[i] = h;
  lo[i] = f2bf(v - bf2f(h));
}

// ---------------- depthwise 3x3 conv + transpose to channel-last, split out ----
__global__ __launch_bounds__(256) void conv_k(
    const float* __restrict__ x, const float* __restrict__ dww,
    const float* __restrict__ dwb, ushort* __restrict__ xc)
{
  __shared__ float xs[3][58][33];
  __shared__ float wgt[32][9];
  __shared__ float wb[32];
  int t = threadIdx.x;
  int c0 = blockIdx.x * 32, h = blockIdx.y, b = blockIdx.z;
  for (int idx = t; idx < 1344; idx += 256) {
    int wq = idx % 14, rem = idx / 14;
    int dy = rem % 3, ch = rem / 3;
    int gh = h + dy - 1;
    float4 v = {0.f, 0.f, 0.f, 0.f};
    if (gh >= 0 && gh < HH)
      v = *(const float4*)(x + (((size_t)b*CD + c0 + ch)*HH + gh)*WS_W + wq*4);
    int wp = wq*4 + 1;
    xs[dy][wp+0][ch] = v.x;
    xs[dy][wp+1][ch] = v.y;
    xs[dy][wp+2][ch] = v.z;
    xs[dy][wp+3][ch] = v.w;
  }
  if (t < 192) {
    int e = t & 1, dy = (t >> 1) % 3, ch = t / 6;
    xs[dy][e*57][ch] = 0.f;
  }
  for (int idx = t; idx < 288; idx += 256)
    wgt[idx/9][idx%9] = dww[(size_t)(c0 + idx/9)*9 + idx%9];
  if (t < 32) wb[t] = dwb[c0 + t];
  __syncthreads();
  int ch = t & 31, wq8 = t >> 5;
  #pragma unroll
  for (int wwi = 0; wwi < 7; ++wwi) {
    int w = wwi*8 + wq8;
    float acc = wb[ch];
    #pragma unroll
    for (int dy = 0; dy < 3; ++dy)
      #pragma unroll
      for (int dx = 0; dx < 3; ++dx)
        acc = fmaf(wgt[ch][dy*3+dx], xs[dy][w+dx][ch], acc);
    size_t oi = ((size_t)b*HWS + h*WS_W + w)*CD + c0 + ch;
    ushort hh = f2bf(acc);
    xc[oi] = hh;
    xc[SLOT + oi] = f2bf(acc - bf2f(hh));
  }
}

// ---------------- fp32 tiled GEMM (tok path only, EPI 2) ---------
template<int EPI>
__global__ __launch_bounds__(256) void gemm_k(
    const float* __restrict__ A, const float* __restrict__ Bw,
    const float* __restrict__ bias, float* __restrict__ out0,
    float* __restrict__ out1, const float* __restrict__ cptr)
{
  __shared__ float As[16][68];
  __shared__ float Bs[16][68];
  int t = threadIdx.x;
  int col0 = blockIdx.x * 64;
  int row0 = blockIdx.y * 64;
  int lr = t >> 2, lk = (t & 3) * 4;
  const float* Ap = A + (size_t)(row0 + lr)*CD + lk;
  const float* Bp = Bw + (size_t)(col0 + lr)*CD + lk;
  float acc[4][4] = {};
  int tx = t & 15, ty = t >> 4;
  for (int k0 = 0; k0 < CD; k0 += 16) {
    float4 av = *(const float4*)(Ap + k0);
    float4 bv = *(const float4*)(Bp + k0);
    __syncthreads();
    As[lk+0][lr] = av.x; As[lk+1][lr] = av.y; As[lk+2][lr] = av.z; As[lk+3][lr] = av.w;
    Bs[lk+0][lr] = bv.x; Bs[lk+1][lr] = bv.y; Bs[lk+2][lr] = bv.z; Bs[lk+3][lr] = bv.w;
    __syncthreads();
    #pragma unroll
    for (int k = 0; k < 16; ++k) {
      float4 a4 = *(const float4*)&As[k][ty*4];
      float4 b4 = *(const float4*)&Bs[k][tx*4];
      float aa[4] = {a4.x, a4.y, a4.z, a4.w};
      float bbv[4] = {b4.x, b4.y, b4.z, b4.w};
      #pragma unroll
      for (int i = 0; i < 4; ++i)
        #pragma unroll
        for (int j = 0; j < 4; ++j)
          acc[i][j] = fmaf(aa[i], bbv[j], acc[i][j]);
    }
  }
  float cs = 0.f;
  if constexpr (EPI == 2) cs = cptr[0];
  #pragma unroll
  for (int i = 0; i < 4; ++i) {
    int r = row0 + ty*4 + i;
    #pragma unroll
    for (int j = 0; j < 4; ++j) {
      int cg = col0 + tx*4 + j;
      float v = acc[i][j];
      if constexpr (EPI == 2) {
        v += bias[cg];
        v = fmaxf(v, 0.f);
        int pi = r / 56, pj = r % 56;
        float wn = 3.14159265358979323846f/56.f * (float)pi;
        float wm = 3.14159265358979323846f/56.f * (float)pj;
        float dec = expf(-(wn*wn + wm*wm));
        out0[(size_t)r*CD + cg] = cosf(cs*v)*dec;
        out1[(size_t)r*CD + cg] = sinf(cs*v)/(cs + 1e-6f)*dec;
      }
    }
  }
}

// ---------------- split-bf16 MFMA GEMM (16x16x32): C = A @ W^T ----------------
// EPI 0/1: A = activations (row0 over 50176), W = weights (col0 over N).
// EPI 3: OPERANDS SWAPPED: A = weights (row0 over 384), W = gated (col0 over
// 50176) -> C^T with 16 consecutive hw per 16-lane group = coalesced NCHW.
template<int EPI>
__global__ __launch_bounds__(256, 2) void mgemm_k(
    const ushort* __restrict__ Ah_g, const ushort* __restrict__ Al_g,
    const ushort* __restrict__ Wh, const ushort* __restrict__ Wl,
    const float* __restrict__ bias,
    float* __restrict__ out0, float* __restrict__ out1,
    const ushort* __restrict__ UinH, const float* __restrict__ cosD,
    const float* __restrict__ sinD, const float* __restrict__ velb,
    const float* __restrict__ alphap)
{
  __shared__ char smem[32768];
  int t = threadIdx.x;
  // bijective XCD swizzle: nwg % 8 == 0 for all launches (2352, 1176)
  int nwg = gridDim.x * gridDim.y;
  int wgid = blockIdx.y * gridDim.x + blockIdx.x;
  int cpx = nwg >> 3;
  int sw = (wgid & 7) * cpx + (wgid >> 3);
  int colT = sw % gridDim.x, rowT = sw / gridDim.x;
  int col0, row0;
  if constexpr (EPI == 3) { row0 = colT * 128; col0 = rowT * 128; }
  else                    { col0 = colT * 128; row0 = rowT * 128; }

  int r = t >> 1, half = t & 1;
  int n = r & 15, rt = r >> 4, q0 = half * 2;
  const ushort* Ahp = Ah_g + (size_t)(row0 + r)*CD + half*16;
  const ushort* Alp = Al_g + (size_t)(row0 + r)*CD + half*16;
  const ushort* Bhp = Wh + (size_t)(col0 + r)*CD + half*16;
  const ushort* Blp = Wl + (size_t)(col0 + r)*CD + half*16;
  int aoff0 = rt*1024 + (q0*16 + n)*16;
  int aoff1 = rt*1024 + ((q0+1)*16 + n)*16;
  int boff0 = 16384 + aoff0, boff1 = 16384 + aoff1;
  int wid = t >> 6, lane = t & 63;
  int wr = wid >> 1, wc = wid & 1;
  f32x4 acc[4][4];
  #pragma unroll
  for (int i = 0; i < 4; ++i)
    #pragma unroll
    for (int j = 0; j < 4; ++j)
      acc[i][j] = (f32x4){0.f, 0.f, 0.f, 0.f};

  for (int k0 = 0; k0 < CD; k0 += 32) {
    uint4 fh0 = *(const uint4*)(Ahp + k0);
    uint4 fh1 = *(const uint4*)(Ahp + k0 + 8);
    uint4 fl0 = *(const uint4*)(Alp + k0);
    uint4 fl1 = *(const uint4*)(Alp + k0 + 8);
    uint4 bh0 = *(const uint4*)(Bhp + k0);
    uint4 bh1 = *(const uint4*)(Bhp + k0 + 8);
    uint4 bl0 = *(const uint4*)(Blp + k0);
    uint4 bl1 = *(const uint4*)(Blp + k0 + 8);
    __syncthreads();
    *(uint4*)(smem + aoff0)        = fh0;
    *(uint4*)(smem + aoff0 + 8192) = fl0;
    *(uint4*)(smem + aoff1)        = fh1;
    *(uint4*)(smem + aoff1 + 8192) = fl1;
    *(uint4*)(smem + boff0)        = bh0;
    *(uint4*)(smem + boff0 + 8192) = bl0;
    *(uint4*)(smem + boff1)        = bh1;
    *(uint4*)(smem + boff1 + 8192) = bl1;
    __syncthreads();
    bf16x8 Ah[4], Al[4], Bh[4], Bl[4];
    #pragma unroll
    for (int i = 0; i < 4; ++i) {
      int ao = (wr*4 + i)*1024 + lane*16;
      Ah[i] = *(const bf16x8*)(smem + ao);
      Al[i] = *(const bf16x8*)(smem + ao + 8192);
      int bo = 16384 + (wc*4 + i)*1024 + lane*16;
      Bh[i] = *(const bf16x8*)(smem + bo);
      Bl[i] = *(const bf16x8*)(smem + bo + 8192);
    }
    #pragma unroll
    for (int i = 0; i < 4; ++i)
      #pragma unroll
      for (int j = 0; j < 4; ++j) {
        acc[i][j] = __builtin_amdgcn_mfma_f32_16x16x32_bf16(Ah[i], Bh[j], acc[i][j], 0, 0, 0);
        acc[i][j] = __builtin_amdgcn_mfma_f32_16x16x32_bf16(Ah[i], Bl[j], acc[i][j], 0, 0, 0);
        acc[i][j] = __builtin_amdgcn_mfma_f32_16x16x32_bf16(Al[i], Bh[j], acc[i][j], 0, 0, 0);
      }
  }

  int nn = lane & 15, qq = lane >> 4;
  float ahalf = 0.f;
  if constexpr (EPI == 1) ahalf = 0.5f * alphap[0];
  #pragma unroll
  for (int i = 0; i < 4; ++i) {
    #pragma unroll
    for (int j = 0; j < 4; ++j) {
      #pragma unroll
      for (int reg = 0; reg < 4; ++reg) {
        float v = acc[i][j][reg];
        if constexpr (EPI == 3) {
          int m  = row0 + wr*64 + i*16 + qq*4 + reg;   // output channel (<384)
          int ng = col0 + wc*64 + j*16 + nn;           // flattened row (<50176)
          v += bias[m];
          int bidx = ng / HWS, hw = ng % HWS;
          out0[((size_t)bidx*CD + m)*HWS + hw] = v;
        } else {
          int rg = row0 + wr*64 + i*16 + qq*4 + reg;
          int cg = col0 + wc*64 + j*16 + nn;
          if constexpr (EPI == 0) {
            v += bias[cg];
            if (cg < CD) out0[(size_t)rg*CD + cg] = v;
            else         out1[(size_t)rg*CD + cg - CD] = v;
          } else {
            int p = rg % HWS;
            size_t uidx = (size_t)rg*CD + cg;
            float u  = bf2f(UinH[uidx]) + bf2f(UinH[SLOT + uidx]);
            float cd = cosD[(size_t)p*CD + cg];
            float sd = sinD[(size_t)p*CD + cg];
            if (p == 0) v += 56.f * velb[cg];
            out0[uidx] = cd*u + sd*(v + ahalf*u);   // F fp32, channel-last
          }
        }
      }
    }
  }
}

// ---------------- DCT pass as MFMA GEMM: OUT = D~ @ IN per batch --------------
template<int OSPLIT>
__global__ __launch_bounds__(256, 3) void dmm_k(
    const float* __restrict__ in, float* __restrict__ outf,
    const ushort* __restrict__ Dpk, int NBT, int RS, size_t BSTR)
{
  __shared__ char smem[49152];     // B hi 16K | B lo 16K | A hi 8K | A lo 8K
  int t = threadIdx.x;
  int flat = blockIdx.x;           // 2688 blocks, %8==0
  int sw = (flat & 7) * 336 + (flat >> 3);
  int batch = sw / NBT, nt0 = sw - batch*NBT;
  int n0 = nt0 * 128;
  const float* inb = in + (size_t)batch*BSTR;
  int wid = t >> 6, lane = t & 63;

  {
    const char* src = (const char*)Dpk;
    #pragma unroll
    for (int i = 0; i < 4; ++i)
      gl16(src + wid*4096 + i*1024 + lane*16,
           smem + 32768 + wid*4096 + i*1024);
  }

  {
    int koct = t >> 5, c4 = (t & 31) * 4;
    float4 fr[8];
    if (koct < 7) {
      #pragma unroll
      for (int j = 0; j < 8; ++j)
        fr[j] = *(const float4*)(inb + (size_t)(koct*8 + j)*RS + n0 + c4);
    } else {
      #pragma unroll
      for (int j = 0; j < 8; ++j) fr[j] = (float4){0.f,0.f,0.f,0.f};
    }
    #pragma unroll
    for (int c = 0; c < 4; ++c) {
      ushort hs[8], ls[8];
      #pragma unroll
      for (int j = 0; j < 8; ++j) {
        float v = ((const float*)&fr[j])[c];
        hs[j] = f2bf(v);
        ls[j] = f2bf(v - bf2f(hs[j]));
      }
      uint4 hv, lv;
      hv.x = hs[0]|((uint)hs[1]<<16); hv.y = hs[2]|((uint)hs[3]<<16);
      hv.z = hs[4]|((uint)hs[5]<<16); hv.w = hs[6]|((uint)hs[7]<<16);
      lv.x = ls[0]|((uint)ls[1]<<16); lv.y = ls[2]|((uint)ls[3]<<16);
      lv.z = ls[4]|((uint)ls[5]<<16); lv.w = ls[6]|((uint)ls[7]<<16);
      int nn = c4 + c;
      int off = (nn >> 4)*2048 + (koct*16 + ((nn & 15) ^ koct))*16;
      *(uint4*)(smem + off)         = hv;
      *(uint4*)(smem + 16384 + off) = lv;
    }
  }
  __syncthreads();

  int mg = wid;
  bf16x8 Ah[2], Al[2];
  #pragma unroll
  for (int ks = 0; ks < 2; ++ks) {
    int ao = 32768 + mg*2048 + ((ks*4 + (lane>>4))*16 + (lane&15))*16;
    Ah[ks] = *(const bf16x8*)(smem + ao);
    Al[ks] = *(const bf16x8*)(smem + ao + 8192);
  }
  f32x4 acc[8];
  #pragma unroll
  for (int nt = 0; nt < 8; ++nt) acc[nt] = (f32x4){0.f,0.f,0.f,0.f};
  #pragma unroll
  for (int nt = 0; nt < 8; ++nt) {
    #pragma unroll
    for (int ks = 0; ks < 2; ++ks) {
      int koctr = ks*4 + (lane>>4);
      int bo = nt*2048 + (koctr*16 + ((lane & 15) ^ koctr))*16;
      bf16x8 Bh = *(const bf16x8*)(smem + bo);
      bf16x8 Bl = *(const bf16x8*)(smem + bo + 16384);
      acc[nt] = __builtin_amdgcn_mfma_f32_16x16x32_bf16(Ah[ks], Bh, acc[nt], 0, 0, 0);
      acc[nt] = __builtin_amdgcn_mfma_f32_16x16x32_bf16(Ah[ks], Bl, acc[nt], 0, 0, 0);
      acc[nt] = __builtin_amdgcn_mfma_f32_16x16x32_bf16(Al[ks], Bh, acc[nt], 0, 0, 0);
      acc[nt] = __builtin_amdgcn_mfma_f32_16x16x32_bf16(Al[ks], Bl, acc[nt], 0, 0, 0);
    }
  }

  int q = lane >> 4, n16 = lane & 15;
  #pragma unroll
  for (int nt = 0; nt < 8; ++nt) {
    #pragma unroll
    for (int reg = 0; reg < 4; ++reg) {
      int m = mg*16 + q*4 + reg;
      if (m < 56) {
        size_t addr = (size_t)batch*BSTR + (size_t)m*RS + n0 + nt*16 + n16;
        float v = acc[nt][reg];
        if constexpr (OSPLIT == 0) {
          outf[addr] = v;
        } else {
          ushort* oh = (ushort*)outf;
          ushort hh = f2bf(v);
          oh[addr] = hh;
          oh[SLOT + addr] = f2bf(v - bf2f(hh));
        }
      }
    }
  }
}

// ---------------- fused IDCT-cols + LayerNorm + SiLU gate ---------------------
// in = T3 [896 batches (b*56+h)][56 w-freq rows][384 c]; one block per batch.
// Computes Y rows (w), then LN over c per row, gate with z, writes gated split.
__global__ __launch_bounds__(256, 1) void dmm_ln_k(
    const float* __restrict__ in, const float* __restrict__ Z,
    const float* __restrict__ g, const float* __restrict__ be,
    ushort* __restrict__ outg, const ushort* __restrict__ Dpk)
{
  __shared__ char smem[117760];
  // B hi 0..49151 | B lo 49152..98303 | A hi 98304 (lo +8192) | g 114688 | be 116224
  int t = threadIdx.x;
  int flat = blockIdx.x;               // 896 = 8*112
  int bt = (flat & 7) * 112 + (flat >> 3);
  const float* inb = in + (size_t)bt * 21504;
  int wid = t >> 6, lane = t & 63;

  // stage A (prepacked inverse D, 16KB)
  {
    const char* src = (const char*)Dpk;
    #pragma unroll
    for (int i = 0; i < 4; ++i)
      gl16(src + wid*4096 + i*1024 + lane*16,
           smem + 98304 + wid*4096 + i*1024);
  }
  // stage g, be (384 f32 each)
  if (t < 96) {
    ((float4*)(smem + 114688))[t] = ((const float4*)g)[t];
    ((float4*)(smem + 116224))[t] = ((const float4*)be)[t];
  }
  // stage B: 3 chunks of 128 cols, same swizzled layout as dmm_k
  for (int ch = 0; ch < 3; ++ch) {
    int koct = t >> 5, c4 = (t & 31) * 4;
    float4 fr[8];
    if (koct < 7) {
      #pragma unroll
      for (int j = 0; j < 8; ++j)
        fr[j] = *(const float4*)(inb + (size_t)(koct*8 + j)*CD + ch*128 + c4);
    } else {
      #pragma unroll
      for (int j = 0; j < 8; ++j) fr[j] = (float4){0.f,0.f,0.f,0.f};
    }
    #pragma unroll
    for (int c = 0; c < 4; ++c) {
      ushort hs[8], ls[8];
      #pragma unroll
      for (int j = 0; j < 8; ++j) {
        float v = ((const float*)&fr[j])[c];
        hs[j] = f2bf(v);
        ls[j] = f2bf(v - bf2f(hs[j]));
      }
      uint4 hv, lv;
      hv.x = hs[0]|((uint)hs[1]<<16); hv.y = hs[2]|((uint)hs[3]<<16);
      hv.z = hs[4]|((uint)hs[5]<<16); hv.w = hs[6]|((uint)hs[7]<<16);
      lv.x = ls[0]|((uint)ls[1]<<16); lv.y = ls[2]|((uint)ls[3]<<16);
      lv.z = ls[4]|((uint)ls[5]<<16); lv.w = ls[6]|((uint)ls[7]<<16);
      int nn = c4 + c;
      int off = ch*16384 + (nn >> 4)*2048 + (koct*16 + ((nn & 15) ^ koct))*16;
      *(uint4*)(smem + off)         = hv;
      *(uint4*)(smem + 49152 + off) = lv;
    }
  }
  __syncthreads();

  int mg = wid;
  bf16x8 Ah[2], Al[2];
  #pragma unroll
  for (int ks = 0; ks < 2; ++ks) {
    int ao = 98304 + mg*2048 + ((ks*4 + (lane>>4))*16 + (lane&15))*16;
    Ah[ks] = *(const bf16x8*)(smem + ao);
    Al[ks] = *(const bf16x8*)(smem + ao + 8192);
  }
  f32x4 acc[24];
  #pragma unroll
  for (int nt = 0; nt < 24; ++nt) acc[nt] = (f32x4){0.f,0.f,0.f,0.f};
  #pragma unroll
  for (int nt = 0; nt < 24; ++nt) {
    #pragma unroll
    for (int ks = 0; ks < 2; ++ks) {
      int koctr = ks*4 + (lane>>4);
      int bo = (nt >> 3)*16384 + (nt & 7)*2048 + (koctr*16 + ((lane & 15) ^ koctr))*16;
      bf16x8 Bh = *(const bf16x8*)(smem + bo);
      bf16x8 Bl = *(const bf16x8*)(smem + bo + 49152);
      acc[nt] = __builtin_amdgcn_mfma_f32_16x16x32_bf16(Ah[ks], Bh, acc[nt], 0, 0, 0);
      acc[nt] = __builtin_amdgcn_mfma_f32_16x16x32_bf16(Ah[ks], Bl, acc[nt], 0, 0, 0);
      acc[nt] = __builtin_amdgcn_mfma_f32_16x16x32_bf16(Al[ks], Bh, acc[nt], 0, 0, 0);
      acc[nt] = __builtin_amdgcn_mfma_f32_16x16x32_bf16(Al[ks], Bl, acc[nt], 0, 0, 0);
    }
  }

  // epilogue: LN over 384 c per row m, gate with z, write gated split
  int q = lane >> 4, n16 = lane & 15;
  int b = bt / 56, h = bt % 56;
  size_t rowbase = ((size_t)b*HWS + (size_t)h*56) * CD;
  const float* gs = (const float*)(smem + 114688);
  const float* bs = (const float*)(smem + 116224);
  #pragma unroll
  for (int reg = 0; reg < 4; ++reg) {
    int m = mg*16 + q*4 + reg;
    float s = 0.f;
    #pragma unroll
    for (int nt = 0; nt < 24; ++nt) s += acc[nt][reg];
    #pragma unroll
    for (int off = 8; off > 0; off >>= 1) s += __shfl_xor(s, off, 64);
    float mu = s * (1.f/384.f);
    float s2 = 0.f;
    #pragma unroll
    for (int nt = 0; nt < 24; ++nt) { float d = acc[nt][reg] - mu; s2 += d*d; }
    #pragma unroll
    for (int off = 8; off > 0; off >>= 1) s2 += __shfl_xor(s2, off, 64);
    float rs = 1.f / sqrtf(s2*(1.f/384.f) + 1e-5f);
    if (m < 56) {
      size_t rb = rowbase + (size_t)m*CD;
      #pragma unroll
      for (int nt = 0; nt < 24; ++nt) {
        int c = nt*16 + n16;
        float yn = (acc[nt][reg] - mu)*rs*gs[c] + bs[c];
        float zv = Z[rb + c];
        float sz = zv / (1.f + expf(-zv));
        float gv = yn*sz;
        ushort hh = f2bf(gv);
        outg[rb + c] = hh;
        outg[SLOT + rb + c] = f2bf(gv - bf2f(hh));
      }
    }
  }
}

extern "C" void kernel_launch(void* const* d_in, const int* in_sizes, int n_in,
                              void* d_out, int out_size, void* d_ws, size_t ws_size,
                              hipStream_t stream) {
  const float* x     = (const float*)d_in[0];
  const float* fe    = (const float*)d_in[1];
  const float* dw_w  = (const float*)d_in[2];
  const float* dw_b  = (const float*)d_in[3];
  const float* lin_w = (const float*)d_in[4];
  const float* lin_b = (const float*)d_in[5];
  const float* vel_w = (const float*)d_in[6];
  const float* vel_b = (const float*)d_in[7];
  const float* tok_w = (const float*)d_in[8];
  const float* tok_b = (const float*)d_in[9];
  const float* ln_g  = (const float*)d_in[10];
  const float* ln_b  = (const float*)d_in[11];
  const float* out_w = (const float*)d_in[12];
  const float* out_b = (const float*)d_in[13];
  const float* cp    = (const float*)d_in[14];
  const float* ap    = (const float*)d_in[15];

  float* ws    = (float*)d_ws;
  float* slotA = ws;                 // xc(split) -> T1 -> F -> gated(split)
  float* slotB = ws + SLOT;          // xg -> U(split) -> T3
  float* slotC = ws + 2*SLOT;        // z
  float* Dm    = ws + 3*SLOT;
  float* cosD  = Dm + 3136;
  float* sinD  = cosD + (size_t)HWS*CD;
  ushort* whi  = (ushort*)(sinD + (size_t)HWS*CD);
  ushort* wlo  = whi + 589824;
  ushort* Dpk  = wlo + 589824;       // 16384 u16 (two orient packs)

  ushort* xcH = (ushort*)slotA;      // conv out split planes (ch-last)
  ushort* UH  = (ushort*)slotB;      // U split planes (ch-last)
  ushort* GH  = (ushort*)slotA;      // gated split planes (ch-last)

  prep_d_k<<<1, 256, 0, stream>>>(Dm);
  prep_pack_k<<<1, 256, 0, stream>>>(Dm, Dpk);
  split_w_k<<<1152, 256, 0, stream>>>(lin_w, whi,          wlo,          294912);
  split_w_k<<< 576, 256, 0, stream>>>(vel_w, whi + 294912, wlo + 294912, 147456);
  split_w_k<<< 576, 256, 0, stream>>>(out_w, whi + 442368, wlo + 442368, 147456);

  // conv(x) -> channel-last xc split planes (slotA)
  conv_k<<<dim3(12, 56, 16), 256, 0, stream>>>(x, dw_w, dw_b, xcH);
  // tok path: cos/sin*decay maps
  gemm_k<2><<<dim3(6, 49), 256, 0, stream>>>(fe, tok_w, tok_b, cosD, sinD, cp);
  // lin: xz = xc @ lin_w^T + lin_b -> xg (slotB fp32), z (slotC)
  mgemm_k<0><<<dim3(6, 392), 256, 0, stream>>>(xcH, xcH + SLOT, whi, wlo, lin_b,
      slotB, slotC, nullptr, nullptr, nullptr, nullptr, nullptr);
  // forward DCT via MFMA: A1 rows (xg -> T1 slotA), A2 cols (T1 -> U split slotB)
  dmm_k<0><<<2688, 256, 0, stream>>>(slotB, slotA, Dpk,        168, 21504, (size_t)1204224);
  dmm_k<1><<<2688, 256, 0, stream>>>(slotA, slotB, Dpk,          3,   384, (size_t)21504);
  // vel in freq domain + fused modulation -> F (slotA, fp32 channel-last)
  mgemm_k<1><<<dim3(3, 392), 256, 0, stream>>>(UH, UH + SLOT, whi + 294912, wlo + 294912,
      nullptr, slotA, nullptr, UH, cosD, sinD, vel_b, ap);
  // inverse DCT pass 1: F (slotA) -> T3 (slotB)
  dmm_k<0><<<2688, 256, 0, stream>>>(slotA, slotB, Dpk + 8192, 168, 21504, (size_t)1204224);
  // fused inverse DCT pass 2 + LayerNorm + SiLU gate -> gated split (slotA)
  dmm_ln_k<<<896, 256, 0, stream>>>(slotB, slotC, ln_g, ln_b, GH, Dpk + 8192);
  // out GEMM (operand-swapped) -> d_out [B,C,H,W]
  mgemm_k<3><<<dim3(3, 392), 256, 0, stream>>>(whi + 442368, wlo + 442368, GH, GH + SLOT,
      out_b, (float*)d_out, nullptr, nullptr, nullptr, nullptr, nullptr, nullptr);
}

// Round 9
// 660.267 us; speedup vs baseline: 1.0696x; 1.0696x over previous
//
#include <hip/hip_runtime.h>
#include <math.h>

#define HH 56
#define WS_W 56
#define HWS 3136
#define CD 384
#define BB 16
#define NROW (BB*HWS)                 // 50176
#define SLOT ((size_t)NROW*CD)        // 19267584 elements

typedef __attribute__((ext_vector_type(8))) short bf16x8;
typedef __attribute__((ext_vector_type(4))) float f32x4;

__device__ inline ushort f2bf(float v) {
  uint u = __float_as_uint(v);
  uint r = (u + 0x7fffu + ((u >> 16) & 1u)) >> 16;
  return (ushort)r;
}
__device__ inline float bf2f(ushort h) { return __uint_as_float((uint)h << 16); }

// direct global -> LDS DMA, 16B per lane; LDS dest = wave-uniform base + lane*16
__device__ inline void gl16(const void* g, void* l) {
  __builtin_amdgcn_global_load_lds(
      (const __attribute__((address_space(1))) void*)g,
      (__attribute__((address_space(3))) void*)l,
      16, 0, 0);
}

// ---------------- DCT matrix ----------
__global__ void prep_d_k(float* __restrict__ D) {
  for (int idx = threadIdx.x; idx < HH*HH; idx += blockDim.x) {
    int k = idx / HH, n = idx % HH;
    double v = cos(3.14159265358979323846 * (2.0*n + 1.0) * k / (2.0*HH)) * sqrt(2.0/HH);
    if (k == 0) v *= 0.70710678118654752440;
    D[idx] = (float)v;
  }
}

// ---------------- D fragment-ready pack: [orient][hi 4096 u16][lo 4096 u16] ---
// A-operand LDS layout: off_u16 = mg*1024 + (koct*16 + m16)*8 + j
__global__ void prep_pack_k(const float* __restrict__ Dm, ushort* __restrict__ Dpk) {
  for (int idx = threadIdx.x; idx < 2*4096; idx += 256) {
    int o = idx >> 12, e = idx & 4095;
    int mg = e >> 10, rem = e & 1023;
    int j = rem & 7, km = rem >> 3;
    int koct = km >> 4, m16 = km & 15;
    int m = mg*16 + m16, k = koct*8 + j;
    float v = 0.f;
    if (m < 56 && k < 56) v = o ? Dm[k*56 + m] : Dm[m*56 + k];
    ushort h = f2bf(v);
    Dpk[o*8192 + e] = h;
    Dpk[o*8192 + 4096 + e] = f2bf(v - bf2f(h));
  }
}

// ---------------- weight split fp32 -> bf16 hi/lo ----------------
__global__ __launch_bounds__(256) void split_w_k(
    const float* __restrict__ W, ushort* __restrict__ hi,
    ushort* __restrict__ lo, int nelem) {
  int i = blockIdx.x*256 + threadIdx.x;
  if (i >= nelem) return;
  float v = W[i];
  ushort h = f2bf(v);
  hi[i] = h;
  lo[i] = f2bf(v - bf2f(h));
}

// ---------------- depthwise 3x3 conv + transpose to channel-last, split out ----
__global__ __launch_bounds__(256) void conv_k(
    const float* __restrict__ x, const float* __restrict__ dww,
    const float* __restrict__ dwb, ushort* __restrict__ xc)
{
  __shared__ float xs[3][58][33];
  __shared__ float wgt[32][9];
  __shared__ float wb[32];
  int t = threadIdx.x;
  int c0 = blockIdx.x * 32, h = blockIdx.y, b = blockIdx.z;
  for (int idx = t; idx < 1344; idx += 256) {
    int wq = idx % 14, rem = idx / 14;
    int dy = rem % 3, ch = rem / 3;
    int gh = h + dy - 1;
    float4 v = {0.f, 0.f, 0.f, 0.f};
    if (gh >= 0 && gh < HH)
      v = *(const float4*)(x + (((size_t)b*CD + c0 + ch)*HH + gh)*WS_W + wq*4);
    int wp = wq*4 + 1;
    xs[dy][wp+0][ch] = v.x;
    xs[dy][wp+1][ch] = v.y;
    xs[dy][wp+2][ch] = v.z;
    xs[dy][wp+3][ch] = v.w;
  }
  if (t < 192) {
    int e = t & 1, dy = (t >> 1) % 3, ch = t / 6;
    xs[dy][e*57][ch] = 0.f;
  }
  for (int idx = t; idx < 288; idx += 256)
    wgt[idx/9][idx%9] = dww[(size_t)(c0 + idx/9)*9 + idx%9];
  if (t < 32) wb[t] = dwb[c0 + t];
  __syncthreads();
  int ch = t & 31, wq8 = t >> 5;
  #pragma unroll
  for (int wwi = 0; wwi < 7; ++wwi) {
    int w = wwi*8 + wq8;
    float acc = wb[ch];
    #pragma unroll
    for (int dy = 0; dy < 3; ++dy)
      #pragma unroll
      for (int dx = 0; dx < 3; ++dx)
        acc = fmaf(wgt[ch][dy*3+dx], xs[dy][w+dx][ch], acc);
    size_t oi = ((size_t)b*HWS + h*WS_W + w)*CD + c0 + ch;
    ushort hh = f2bf(acc);
    xc[oi] = hh;
    xc[SLOT + oi] = f2bf(acc - bf2f(hh));
  }
}

// ---------------- fp32 tiled GEMM (tok path only, EPI 2) ---------
template<int EPI>
__global__ __launch_bounds__(256) void gemm_k(
    const float* __restrict__ A, const float* __restrict__ Bw,
    const float* __restrict__ bias, float* __restrict__ out0,
    float* __restrict__ out1, const float* __restrict__ cptr)
{
  __shared__ float As[16][68];
  __shared__ float Bs[16][68];
  int t = threadIdx.x;
  int col0 = blockIdx.x * 64;
  int row0 = blockIdx.y * 64;
  int lr = t >> 2, lk = (t & 3) * 4;
  const float* Ap = A + (size_t)(row0 + lr)*CD + lk;
  const float* Bp = Bw + (size_t)(col0 + lr)*CD + lk;
  float acc[4][4] = {};
  int tx = t & 15, ty = t >> 4;
  for (int k0 = 0; k0 < CD; k0 += 16) {
    float4 av = *(const float4*)(Ap + k0);
    float4 bv = *(const float4*)(Bp + k0);
    __syncthreads();
    As[lk+0][lr] = av.x; As[lk+1][lr] = av.y; As[lk+2][lr] = av.z; As[lk+3][lr] = av.w;
    Bs[lk+0][lr] = bv.x; Bs[lk+1][lr] = bv.y; Bs[lk+2][lr] = bv.z; Bs[lk+3][lr] = bv.w;
    __syncthreads();
    #pragma unroll
    for (int k = 0; k < 16; ++k) {
      float4 a4 = *(const float4*)&As[k][ty*4];
      float4 b4 = *(const float4*)&Bs[k][tx*4];
      float aa[4] = {a4.x, a4.y, a4.z, a4.w};
      float bbv[4] = {b4.x, b4.y, b4.z, b4.w};
      #pragma unroll
      for (int i = 0; i < 4; ++i)
        #pragma unroll
        for (int j = 0; j < 4; ++j)
          acc[i][j] = fmaf(aa[i], bbv[j], acc[i][j]);
    }
  }
  float cs = 0.f;
  if constexpr (EPI == 2) cs = cptr[0];
  #pragma unroll
  for (int i = 0; i < 4; ++i) {
    int r = row0 + ty*4 + i;
    #pragma unroll
    for (int j = 0; j < 4; ++j) {
      int cg = col0 + tx*4 + j;
      float v = acc[i][j];
      if constexpr (EPI == 2) {
        v += bias[cg];
        v = fmaxf(v, 0.f);
        int pi = r / 56, pj = r % 56;
        float wn = 3.14159265358979323846f/56.f * (float)pi;
        float wm = 3.14159265358979323846f/56.f * (float)pj;
        float dec = expf(-(wn*wn + wm*wm));
        out0[(size_t)r*CD + cg] = cosf(cs*v)*dec;
        out1[(size_t)r*CD + cg] = sinf(cs*v)/(cs + 1e-6f)*dec;
      }
    }
  }
}

// ---------------- split-bf16 MFMA GEMM (16x16x32): C = A @ W^T ----------------
// EPI 0/1: A = activations (row0 over 50176), W = weights (col0 over N).
// EPI 3: OPERANDS SWAPPED: A = weights (row0 over 384), W = gated (col0 over
// 50176) -> C^T with 16 consecutive hw per 16-lane group = coalesced NCHW.
template<int EPI>
__global__ __launch_bounds__(256, 2) void mgemm_k(
    const ushort* __restrict__ Ah_g, const ushort* __restrict__ Al_g,
    const ushort* __restrict__ Wh, const ushort* __restrict__ Wl,
    const float* __restrict__ bias,
    float* __restrict__ out0, float* __restrict__ out1,
    const ushort* __restrict__ UinH, const float* __restrict__ cosD,
    const float* __restrict__ sinD, const float* __restrict__ velb,
    const float* __restrict__ alphap)
{
  __shared__ char smem[32768];
  int t = threadIdx.x;
  // bijective XCD swizzle: nwg % 8 == 0 for all launches (2352, 1176)
  int nwg = gridDim.x * gridDim.y;
  int wgid = blockIdx.y * gridDim.x + blockIdx.x;
  int cpx = nwg >> 3;
  int sw = (wgid & 7) * cpx + (wgid >> 3);
  int colT = sw % gridDim.x, rowT = sw / gridDim.x;
  int col0, row0;
  if constexpr (EPI == 3) { row0 = colT * 128; col0 = rowT * 128; }
  else                    { col0 = colT * 128; row0 = rowT * 128; }

  int r = t >> 1, half = t & 1;
  int n = r & 15, rt = r >> 4, q0 = half * 2;
  const ushort* Ahp = Ah_g + (size_t)(row0 + r)*CD + half*16;
  const ushort* Alp = Al_g + (size_t)(row0 + r)*CD + half*16;
  const ushort* Bhp = Wh + (size_t)(col0 + r)*CD + half*16;
  const ushort* Blp = Wl + (size_t)(col0 + r)*CD + half*16;
  int aoff0 = rt*1024 + (q0*16 + n)*16;
  int aoff1 = rt*1024 + ((q0+1)*16 + n)*16;
  int boff0 = 16384 + aoff0, boff1 = 16384 + aoff1;
  int wid = t >> 6, lane = t & 63;
  int wr = wid >> 1, wc = wid & 1;
  f32x4 acc[4][4];
  #pragma unroll
  for (int i = 0; i < 4; ++i)
    #pragma unroll
    for (int j = 0; j < 4; ++j)
      acc[i][j] = (f32x4){0.f, 0.f, 0.f, 0.f};

  for (int k0 = 0; k0 < CD; k0 += 32) {
    uint4 fh0 = *(const uint4*)(Ahp + k0);
    uint4 fh1 = *(const uint4*)(Ahp + k0 + 8);
    uint4 fl0 = *(const uint4*)(Alp + k0);
    uint4 fl1 = *(const uint4*)(Alp + k0 + 8);
    uint4 bh0 = *(const uint4*)(Bhp + k0);
    uint4 bh1 = *(const uint4*)(Bhp + k0 + 8);
    uint4 bl0 = *(const uint4*)(Blp + k0);
    uint4 bl1 = *(const uint4*)(Blp + k0 + 8);
    __syncthreads();
    *(uint4*)(smem + aoff0)        = fh0;
    *(uint4*)(smem + aoff0 + 8192) = fl0;
    *(uint4*)(smem + aoff1)        = fh1;
    *(uint4*)(smem + aoff1 + 8192) = fl1;
    *(uint4*)(smem + boff0)        = bh0;
    *(uint4*)(smem + boff0 + 8192) = bl0;
    *(uint4*)(smem + boff1)        = bh1;
    *(uint4*)(smem + boff1 + 8192) = bl1;
    __syncthreads();
    bf16x8 Ah[4], Al[4], Bh[4], Bl[4];
    #pragma unroll
    for (int i = 0; i < 4; ++i) {
      int ao = (wr*4 + i)*1024 + lane*16;
      Ah[i] = *(const bf16x8*)(smem + ao);
      Al[i] = *(const bf16x8*)(smem + ao + 8192);
      int bo = 16384 + (wc*4 + i)*1024 + lane*16;
      Bh[i] = *(const bf16x8*)(smem + bo);
      Bl[i] = *(const bf16x8*)(smem + bo + 8192);
    }
    #pragma unroll
    for (int i = 0; i < 4; ++i)
      #pragma unroll
      for (int j = 0; j < 4; ++j) {
        acc[i][j] = __builtin_amdgcn_mfma_f32_16x16x32_bf16(Ah[i], Bh[j], acc[i][j], 0, 0, 0);
        acc[i][j] = __builtin_amdgcn_mfma_f32_16x16x32_bf16(Ah[i], Bl[j], acc[i][j], 0, 0, 0);
        acc[i][j] = __builtin_amdgcn_mfma_f32_16x16x32_bf16(Al[i], Bh[j], acc[i][j], 0, 0, 0);
      }
  }

  int nn = lane & 15, qq = lane >> 4;
  float ahalf = 0.f;
  if constexpr (EPI == 1) ahalf = 0.5f * alphap[0];
  #pragma unroll
  for (int i = 0; i < 4; ++i) {
    #pragma unroll
    for (int j = 0; j < 4; ++j) {
      #pragma unroll
      for (int reg = 0; reg < 4; ++reg) {
        float v = acc[i][j][reg];
        if constexpr (EPI == 3) {
          int m  = row0 + wr*64 + i*16 + qq*4 + reg;   // output channel (<384)
          int ng = col0 + wc*64 + j*16 + nn;           // flattened row (<50176)
          v += bias[m];
          int bidx = ng / HWS, hw = ng % HWS;
          out0[((size_t)bidx*CD + m)*HWS + hw] = v;
        } else {
          int rg = row0 + wr*64 + i*16 + qq*4 + reg;
          int cg = col0 + wc*64 + j*16 + nn;
          if constexpr (EPI == 0) {
            v += bias[cg];
            if (cg < CD) out0[(size_t)rg*CD + cg] = v;
            else         out1[(size_t)rg*CD + cg - CD] = v;
          } else {
            int p = rg % HWS;
            size_t uidx = (size_t)rg*CD + cg;
            float u  = bf2f(UinH[uidx]) + bf2f(UinH[SLOT + uidx]);
            float cd = cosD[(size_t)p*CD + cg];
            float sd = sinD[(size_t)p*CD + cg];
            if (p == 0) v += 56.f * velb[cg];
            out0[uidx] = cd*u + sd*(v + ahalf*u);   // F fp32, channel-last
          }
        }
      }
    }
  }
}

// ---------------- DCT pass as MFMA GEMM: OUT = D~ @ IN per batch --------------
template<int OSPLIT>
__global__ __launch_bounds__(256, 3) void dmm_k(
    const float* __restrict__ in, float* __restrict__ outf,
    const ushort* __restrict__ Dpk, int NBT, int RS, size_t BSTR)
{
  __shared__ char smem[49152];     // B hi 16K | B lo 16K | A hi 8K | A lo 8K
  int t = threadIdx.x;
  int flat = blockIdx.x;           // 2688 blocks, %8==0
  int sw = (flat & 7) * 336 + (flat >> 3);
  int batch = sw / NBT, nt0 = sw - batch*NBT;
  int n0 = nt0 * 128;
  const float* inb = in + (size_t)batch*BSTR;
  int wid = t >> 6, lane = t & 63;

  {
    const char* src = (const char*)Dpk;
    #pragma unroll
    for (int i = 0; i < 4; ++i)
      gl16(src + wid*4096 + i*1024 + lane*16,
           smem + 32768 + wid*4096 + i*1024);
  }

  {
    int koct = t >> 5, c4 = (t & 31) * 4;
    float4 fr[8];
    if (koct < 7) {
      #pragma unroll
      for (int j = 0; j < 8; ++j)
        fr[j] = *(const float4*)(inb + (size_t)(koct*8 + j)*RS + n0 + c4);
    } else {
      #pragma unroll
      for (int j = 0; j < 8; ++j) fr[j] = (float4){0.f,0.f,0.f,0.f};
    }
    #pragma unroll
    for (int c = 0; c < 4; ++c) {
      ushort hs[8], ls[8];
      #pragma unroll
      for (int j = 0; j < 8; ++j) {
        float v = ((const float*)&fr[j])[c];
        hs[j] = f2bf(v);
        ls[j] = f2bf(v - bf2f(hs[j]));
      }
      uint4 hv, lv;
      hv.x = hs[0]|((uint)hs[1]<<16); hv.y = hs[2]|((uint)hs[3]<<16);
      hv.z = hs[4]|((uint)hs[5]<<16); hv.w = hs[6]|((uint)hs[7]<<16);
      lv.x = ls[0]|((uint)ls[1]<<16); lv.y = ls[2]|((uint)ls[3]<<16);
      lv.z = ls[4]|((uint)ls[5]<<16); lv.w = ls[6]|((uint)ls[7]<<16);
      int nn = c4 + c;
      int off = (nn >> 4)*2048 + (koct*16 + ((nn & 15) ^ koct))*16;
      *(uint4*)(smem + off)         = hv;
      *(uint4*)(smem + 16384 + off) = lv;
    }
  }
  __syncthreads();

  int mg = wid;
  bf16x8 Ah[2], Al[2];
  #pragma unroll
  for (int ks = 0; ks < 2; ++ks) {
    int ao = 32768 + mg*2048 + ((ks*4 + (lane>>4))*16 + (lane&15))*16;
    Ah[ks] = *(const bf16x8*)(smem + ao);
    Al[ks] = *(const bf16x8*)(smem + ao + 8192);
  }
  f32x4 acc[8];
  #pragma unroll
  for (int nt = 0; nt < 8; ++nt) acc[nt] = (f32x4){0.f,0.f,0.f,0.f};
  #pragma unroll
  for (int nt = 0; nt < 8; ++nt) {
    #pragma unroll
    for (int ks = 0; ks < 2; ++ks) {
      int koctr = ks*4 + (lane>>4);
      int bo = nt*2048 + (koctr*16 + ((lane & 15) ^ koctr))*16;
      bf16x8 Bh = *(const bf16x8*)(smem + bo);
      bf16x8 Bl = *(const bf16x8*)(smem + bo + 16384);
      acc[nt] = __builtin_amdgcn_mfma_f32_16x16x32_bf16(Ah[ks], Bh, acc[nt], 0, 0, 0);
      acc[nt] = __builtin_amdgcn_mfma_f32_16x16x32_bf16(Ah[ks], Bl, acc[nt], 0, 0, 0);
      acc[nt] = __builtin_amdgcn_mfma_f32_16x16x32_bf16(Al[ks], Bh, acc[nt], 0, 0, 0);
      acc[nt] = __builtin_amdgcn_mfma_f32_16x16x32_bf16(Al[ks], Bl, acc[nt], 0, 0, 0);
    }
  }

  int q = lane >> 4, n16 = lane & 15;
  #pragma unroll
  for (int nt = 0; nt < 8; ++nt) {
    #pragma unroll
    for (int reg = 0; reg < 4; ++reg) {
      int m = mg*16 + q*4 + reg;
      if (m < 56) {
        size_t addr = (size_t)batch*BSTR + (size_t)m*RS + n0 + nt*16 + n16;
        float v = acc[nt][reg];
        if constexpr (OSPLIT == 0) {
          outf[addr] = v;
        } else {
          ushort* oh = (ushort*)outf;
          ushort hh = f2bf(v);
          oh[addr] = hh;
          oh[SLOT + addr] = f2bf(v - bf2f(hh));
        }
      }
    }
  }
}

// ---------------- LayerNorm over C + SiLU gate, split out ---------------------
__global__ __launch_bounds__(256) void ln_gate_k(
    const float* __restrict__ Y, const float* __restrict__ Z,
    const float* __restrict__ g, const float* __restrict__ be,
    ushort* __restrict__ out)
{
  int lane = threadIdx.x & 63, wv = threadIdx.x >> 6;
  size_t r = (size_t)blockIdx.x*4 + wv;
  const float* y = Y + r*CD;
  float v[6];
  float s = 0.f;
  #pragma unroll
  for (int q = 0; q < 6; ++q) { v[q] = y[lane + 64*q]; s += v[q]; }
  #pragma unroll
  for (int off = 32; off > 0; off >>= 1) s += __shfl_xor(s, off, 64);
  float mu = s * (1.f/384.f);
  float s2 = 0.f;
  #pragma unroll
  for (int q = 0; q < 6; ++q) { float d = v[q]-mu; s2 += d*d; }
  #pragma unroll
  for (int off = 32; off > 0; off >>= 1) s2 += __shfl_xor(s2, off, 64);
  float rs = 1.f / sqrtf(s2*(1.f/384.f) + 1e-5f);
  #pragma unroll
  for (int q = 0; q < 6; ++q) {
    int c = lane + 64*q;
    float yn = (v[q]-mu)*rs*g[c] + be[c];
    float zv = Z[r*CD + c];
    float sz = zv / (1.f + expf(-zv));
    float gv = yn*sz;
    ushort hh = f2bf(gv);
    out[r*CD + c] = hh;
    out[SLOT + r*CD + c] = f2bf(gv - bf2f(hh));
  }
}

extern "C" void kernel_launch(void* const* d_in, const int* in_sizes, int n_in,
                              void* d_out, int out_size, void* d_ws, size_t ws_size,
                              hipStream_t stream) {
  const float* x     = (const float*)d_in[0];
  const float* fe    = (const float*)d_in[1];
  const float* dw_w  = (const float*)d_in[2];
  const float* dw_b  = (const float*)d_in[3];
  const float* lin_w = (const float*)d_in[4];
  const float* lin_b = (const float*)d_in[5];
  const float* vel_w = (const float*)d_in[6];
  const float* vel_b = (const float*)d_in[7];
  const float* tok_w = (const float*)d_in[8];
  const float* tok_b = (const float*)d_in[9];
  const float* ln_g  = (const float*)d_in[10];
  const float* ln_b  = (const float*)d_in[11];
  const float* out_w = (const float*)d_in[12];
  const float* out_b = (const float*)d_in[13];
  const float* cp    = (const float*)d_in[14];
  const float* ap    = (const float*)d_in[15];

  float* ws    = (float*)d_ws;
  float* slotA = ws;                 // xc(split) -> T1 -> F -> Y
  float* slotB = ws + SLOT;          // xg -> U(split) -> T3 -> gated(split)
  float* slotC = ws + 2*SLOT;        // z
  float* Dm    = ws + 3*SLOT;
  float* cosD  = Dm + 3136;
  float* sinD  = cosD + (size_t)HWS*CD;
  ushort* whi  = (ushort*)(sinD + (size_t)HWS*CD);
  ushort* wlo  = whi + 589824;
  ushort* Dpk  = wlo + 589824;       // 16384 u16 (two orient packs)

  ushort* xcH = (ushort*)slotA;      // conv out split planes (ch-last)
  ushort* UH  = (ushort*)slotB;      // U split planes (ch-last)
  ushort* GH  = (ushort*)slotB;      // gated split planes (ch-last)

  prep_d_k<<<1, 256, 0, stream>>>(Dm);
  prep_pack_k<<<1, 256, 0, stream>>>(Dm, Dpk);
  split_w_k<<<1152, 256, 0, stream>>>(lin_w, whi,          wlo,          294912);
  split_w_k<<< 576, 256, 0, stream>>>(vel_w, whi + 294912, wlo + 294912, 147456);
  split_w_k<<< 576, 256, 0, stream>>>(out_w, whi + 442368, wlo + 442368, 147456);

  // conv(x) -> channel-last xc split planes (slotA)
  conv_k<<<dim3(12, 56, 16), 256, 0, stream>>>(x, dw_w, dw_b, xcH);
  // tok path: cos/sin*decay maps
  gemm_k<2><<<dim3(6, 49), 256, 0, stream>>>(fe, tok_w, tok_b, cosD, sinD, cp);
  // lin: xz = xc @ lin_w^T + lin_b -> xg (slotB fp32), z (slotC)
  mgemm_k<0><<<dim3(6, 392), 256, 0, stream>>>(xcH, xcH + SLOT, whi, wlo, lin_b,
      slotB, slotC, nullptr, nullptr, nullptr, nullptr, nullptr);
  // forward DCT via MFMA: A1 rows (xg -> T1 slotA), A2 cols (T1 -> U split slotB)
  dmm_k<0><<<2688, 256, 0, stream>>>(slotB, slotA, Dpk,        168, 21504, (size_t)1204224);
  dmm_k<1><<<2688, 256, 0, stream>>>(slotA, slotB, Dpk,          3,   384, (size_t)21504);
  // vel in freq domain + fused modulation -> F (slotA, fp32 channel-last)
  mgemm_k<1><<<dim3(3, 392), 256, 0, stream>>>(UH, UH + SLOT, whi + 294912, wlo + 294912,
      nullptr, slotA, nullptr, UH, cosD, sinD, vel_b, ap);
  // inverse DCT via MFMA: B1 rows (F -> T3 slotB), B2 cols (T3 -> Y slotA)
  dmm_k<0><<<2688, 256, 0, stream>>>(slotA, slotB, Dpk + 8192, 168, 21504, (size_t)1204224);
  dmm_k<0><<<2688, 256, 0, stream>>>(slotB, slotA, Dpk + 8192,   3,   384, (size_t)21504);
  // LayerNorm + SiLU gate -> gated split (slotB)
  ln_gate_k<<<12544, 256, 0, stream>>>(slotA, slotC, ln_g, ln_b, GH);
  // out GEMM (operand-swapped) -> d_out [B,C,H,W]
  mgemm_k<3><<<dim3(3, 392), 256, 0, stream>>>(whi + 442368, wlo + 442368, GH, GH + SLOT,
      out_b, (float*)d_out, nullptr, nullptr, nullptr, nullptr, nullptr, nullptr);
}